// Round 1
// baseline (1559.975 us; speedup 1.0000x reference)
//
#include <hip/hip_runtime.h>

typedef unsigned short u16;
typedef unsigned int u32;
typedef __attribute__((ext_vector_type(8))) short short8;
typedef __attribute__((ext_vector_type(4))) float f32x4;
typedef __attribute__((ext_vector_type(4))) _Float16 half4;
typedef __attribute__((ext_vector_type(4))) u16 ushort4_t;

// ---------- scalar conversion helpers (bit-level, no header dependence) ----
__device__ __forceinline__ float bf2f(u16 u) {
    u32 x = ((u32)u) << 16;
    return __uint_as_float(x);
}
__device__ __forceinline__ u16 f2bf(float f) {  // round-to-nearest-even
    u32 x = __float_as_uint(f);
    x += 0x7FFFu + ((x >> 16) & 1u);
    return (u16)(x >> 16);
}
__device__ __forceinline__ u16 f2h(float f) {
    _Float16 h = (_Float16)f;
    union { _Float16 h; u16 u; } c; c.h = h;
    return c.u;
}
__device__ __forceinline__ _Float16 u2h(u16 u) {
    union { u16 u; _Float16 h; } c; c.u = u;
    return c.h;
}

// ---------- async global->LDS (16B per lane, wave-uniform base) ------------
using as1_cv = __attribute__((address_space(1))) const void;
using as3_v  = __attribute__((address_space(3))) void;
__device__ __forceinline__ void gld16(const void* g, void* l) {
    __builtin_amdgcn_global_load_lds((as1_cv*)g, (as3_v*)l, 16, 0, 0);
}

// ---------- fp32 -> bf16 convert (4 elems/thread) --------------------------
__global__ void cvt_f32_bf16(const float* __restrict__ in, u16* __restrict__ out, int n4) {
    int i = blockIdx.x * 256 + threadIdx.x;
    if (i >= n4) return;
    float4 v = ((const float4*)in)[i];
    ushort4_t o;
    o[0] = f2bf(v.x); o[1] = f2bf(v.y); o[2] = f2bf(v.z); o[3] = f2bf(v.w);
    ((ushort4_t*)out)[i] = o;
}

// ---------- GEMM: C[M,N] = A[M,K] * B[N,K]^T, bf16 inputs ------------------
// OUT_MODE: 0 = bf16 out, 1 = f32 out, 2 = f16 out
// m97 structure: 128x128 tile, BK=32, 256 thr (4 waves 2x2), 4x4 16x16x32 MFMA.
template <int OUT_MODE>
__global__ __launch_bounds__(256) void gemm_bt(
    const u16* __restrict__ A, const u16* __restrict__ B,
    u16* __restrict__ Cb, float* __restrict__ Cf,
    int M, int N, int K)
{
    __shared__ __align__(16) u16 As[128 * 32];
    __shared__ __align__(16) u16 Bs[128 * 32];
    const int t    = threadIdx.x;
    const int lane = t & 63;
    const int w    = t >> 6;
    const int wm   = w & 1;
    const int wn   = w >> 1;
    const int bx   = blockIdx.x;   // N tile
    const int by   = blockIdx.y;   // M tile

    // staging: thread t covers rows (t>>2) and 64+(t>>2), k-chunk (t&3)*8
    const int r  = t >> 2;
    const int c8 = (t & 3) * 8;
    const u16* gA0 = A + (size_t)(by * 128 + r) * K + c8;
    const u16* gA1 = gA0 + (size_t)64 * K;
    const u16* gB0 = B + (size_t)(bx * 128 + r) * K + c8;
    const u16* gB1 = gB0 + (size_t)64 * K;
    u16* lA0 = &As[t * 8];
    u16* lA1 = &As[2048 + t * 8];
    u16* lB0 = &Bs[t * 8];
    u16* lB1 = &Bs[2048 + t * 8];

    f32x4 acc[4][4] = {};

    const int arow = wm * 64 + (lane & 15);
    const int brow = wn * 64 + (lane & 15);
    const int koff = (lane >> 4) * 8;

    for (int kt = 0; kt < K; kt += 32) {
        gld16(gA0 + kt, lA0);
        gld16(gA1 + kt, lA1);
        gld16(gB0 + kt, lB0);
        gld16(gB1 + kt, lB1);
        __syncthreads();
        short8 af[4], bf[4];
#pragma unroll
        for (int i = 0; i < 4; i++)
            af[i] = *(const short8*)&As[(arow + i * 16) * 32 + koff];
#pragma unroll
        for (int i = 0; i < 4; i++)
            bf[i] = *(const short8*)&Bs[(brow + i * 16) * 32 + koff];
#pragma unroll
        for (int mi = 0; mi < 4; mi++)
#pragma unroll
            for (int ni = 0; ni < 4; ni++)
                acc[mi][ni] = __builtin_amdgcn_mfma_f32_16x16x32_bf16(
                    af[mi], bf[ni], acc[mi][ni], 0, 0, 0);
        __syncthreads();
    }

    // epilogue: D[row=(lane>>4)*4+r][col=lane&15] per 16x16 tile
    const int row0 = by * 128 + wm * 64 + (lane >> 4) * 4;
    const int col0 = bx * 128 + wn * 64 + (lane & 15);
#pragma unroll
    for (int mi = 0; mi < 4; mi++) {
#pragma unroll
        for (int ni = 0; ni < 4; ni++) {
#pragma unroll
            for (int rr = 0; rr < 4; rr++) {
                int row = row0 + mi * 16 + rr;
                int col = col0 + ni * 16;
                float v = acc[mi][ni][rr];
                if (OUT_MODE == 1)      Cf[(size_t)row * N + col] = v;
                else if (OUT_MODE == 0) Cb[(size_t)row * N + col] = f2bf(v);
                else                    Cb[(size_t)row * N + col] = f2h(v);
            }
        }
    }
}

// ---------- RoPE in-place on bf16 [B*S, H*128] -----------------------------
// pair i<64: x[i] = x[i]*cos - x[i+64]*sin ; x[i+64] = x[i+64]*cos + x[i]*sin
__global__ void rope_k(u16* __restrict__ x, int hshift) {
    int idx = blockIdx.x * 256 + threadIdx.x;
    int i   = idx & 63;
    int hm  = (1 << (hshift - 6)) - 1;
    int h   = (idx >> 6) & hm;
    int row = idx >> hshift;       // 0..B*S-1
    int s   = row & 2047;          // position within sequence
    int stride = (hm + 1) * 128;
    size_t base = (size_t)row * stride + h * 128 + i;
    float th = (float)s * powf(10000.0f, -(float)i / 64.0f);
    float cs = cosf(th), sn = sinf(th);
    float x1 = bf2f(x[base]), x2 = bf2f(x[base + 64]);
    x[base]      = f2bf(x1 * cs - x2 * sn);
    x[base + 64] = f2bf(x2 * cs + x1 * sn);
}

// ---------- causal flash attention -----------------------------------------
// grid (S/64, NH, B); 256 thr = 4 waves; wave w owns 16 q-rows.
// Computes S^T = K*Q^T so C-layout(S^T) == B-operand layout of P^T for
// O^T = V^T * P^T (16x16x16 f16 MFMA). Stats (m,l) indexed by q = lane&15,
// consistent across score, rescale, and final layouts.
__global__ __launch_bounds__(256) void flash_attn(
    const u16* __restrict__ qb, const u16* __restrict__ kb,
    const u16* __restrict__ vb, u16* __restrict__ ob)
{
    const int t    = threadIdx.x;
    const int lane = t & 63;
    const int w    = t >> 6;
    const int col  = lane & 15;
    const int g    = lane >> 4;
    const int qtile = blockIdx.x;
    const int qh    = blockIdx.y;
    const int b     = blockIdx.z;
    const int kvh   = qh >> 2;          // G = 4
    const int q0    = qtile * 64 + w * 16;
    const int q     = q0 + col;         // this lane's query

    // Q fragments (B-operand of K*Q^T): Q[q][c*32 + g*8 + j]
    const u16* qrow = qb + ((size_t)(b * 2048 + q)) * 4096 + qh * 128;
    short8 qf[4];
#pragma unroll
    for (int c = 0; c < 4; c++)
        qf[c] = *(const short8*)(qrow + c * 32 + g * 8);

    const u16* kB = kb + ((size_t)b * 2048) * 1024 + kvh * 128;
    const u16* vB = vb + ((size_t)b * 2048) * 1024 + kvh * 128;

    float m_run = -1e30f, l_run = 0.0f;
    f32x4 ot[8] = {};
    const float scale = 0.08838834764831845f;  // 1/sqrt(128)

    for (int k0 = 0; k0 <= q0 + 15; k0 += 16) {
        // K fragment (A-operand): K[k0+col][c*32 + g*8 + j]
        const u16* kr = kB + (size_t)(k0 + col) * 1024;
        f32x4 sc = {0.f, 0.f, 0.f, 0.f};
#pragma unroll
        for (int c = 0; c < 4; c++) {
            short8 kf = *(const short8*)(kr + c * 32 + g * 8);
            sc = __builtin_amdgcn_mfma_f32_16x16x32_bf16(kf, qf[c], sc, 0, 0, 0);
        }
        // sc[r] = S^T[key = k0+g*4+r][query = q]
        float p[4];
        float tmax = -1e30f;
#pragma unroll
        for (int rr = 0; rr < 4; rr++) {
            int key = k0 + g * 4 + rr;
            float v = sc[rr] * scale;
            v = (key <= q) ? v : -1e30f;
            p[rr] = v;
            tmax = fmaxf(tmax, v);
        }
        // per-query max across the 4 lane-groups (same col)
        tmax = fmaxf(tmax, __shfl_xor(tmax, 16));
        tmax = fmaxf(tmax, __shfl_xor(tmax, 32));
        float m_new = fmaxf(m_run, tmax);
        float alpha = __expf(m_run - m_new);
        float tsum = 0.f;
#pragma unroll
        for (int rr = 0; rr < 4; rr++) {
            p[rr] = __expf(p[rr] - m_new);
            tsum += p[rr];
        }
        tsum += __shfl_xor(tsum, 16);
        tsum += __shfl_xor(tsum, 32);
        l_run = l_run * alpha + tsum;
        m_run = m_new;

        // P^T fragment (B-operand of V^T*P^T): PT[k=g*4+j][q] = p[j]
        half4 pf;
#pragma unroll
        for (int j = 0; j < 4; j++) pf[j] = (_Float16)p[j];

#pragma unroll
        for (int dt = 0; dt < 8; dt++)
#pragma unroll
            for (int rr = 0; rr < 4; rr++) ot[dt][rr] *= alpha;

        // V^T fragment (A-operand): V[k0+g*4+j][dt*16+col], f16 bits in vb
        const u16* vr0 = vB + (size_t)(k0 + g * 4) * 1024;
#pragma unroll
        for (int dt = 0; dt < 8; dt++) {
            half4 vf;
#pragma unroll
            for (int j = 0; j < 4; j++)
                vf[j] = u2h(vr0[(size_t)j * 1024 + dt * 16 + col]);
            ot[dt] = __builtin_amdgcn_mfma_f32_16x16x16f16(vf, pf, ot[dt], 0, 0, 0);
        }
    }

    float inv_l = 1.0f / l_run;
    // O^T C-layout: dim = dt*16 + g*4 + rr, query = col
    u16* orow = ob + ((size_t)(b * 2048 + q)) * 4096 + qh * 128;
#pragma unroll
    for (int dt = 0; dt < 8; dt++) {
        ushort4_t o;
#pragma unroll
        for (int rr = 0; rr < 4; rr++) o[rr] = f2bf(ot[dt][rr] * inv_l);
        *(ushort4_t*)(orow + dt * 16 + g * 4) = o;
    }
}

// ---------------------------------------------------------------------------
extern "C" void kernel_launch(void* const* d_in, const int* in_sizes, int n_in,
                              void* d_out, int out_size, void* d_ws, size_t ws_size,
                              hipStream_t stream) {
    const float* hs = (const float*)d_in[0];  // [2,2048,4096]
    const float* Wq = (const float*)d_in[1];  // [4096,4096]
    const float* Wk = (const float*)d_in[2];  // [1024,4096]
    const float* Wv = (const float*)d_in[3];  // [1024,4096]
    const float* Wo = (const float*)d_in[4];  // [4096,4096]
    float* out = (float*)d_out;               // [2,2048,4096]

    char* ws = (char*)d_ws;
    // byte offsets (bf16/f16 buffers)
    u16* hsb = (u16*)(ws + 0);           // 33,554,432 B  [4096,4096]
    u16* Wqb = (u16*)(ws + 33554432);    // 33,554,432 B
    u16* Wkb = (u16*)(ws + 67108864);    //  8,388,608 B
    u16* Wvb = (u16*)(ws + 75497472);    //  8,388,608 B
    u16* Wob = (u16*)(ws + 83886080);    // 33,554,432 B
    u16* qb  = (u16*)(ws + 117440512);   // 33,554,432 B  [4096,4096]
    u16* kbf = (u16*)(ws + 150994944);   //  8,388,608 B  [4096,1024]
    u16* vbf = (u16*)(ws + 159383552);   //  8,388,608 B  [4096,1024] (f16)
    u16* ab  = hsb;                      // alias: hs dead after QKV GEMMs
    // total: 167,772,160 B

    // fp32 -> bf16 conversions
    cvt_f32_bf16<<<16384, 256, 0, stream>>>(hs, hsb, 4194304);
    cvt_f32_bf16<<<16384, 256, 0, stream>>>(Wq, Wqb, 4194304);
    cvt_f32_bf16<<<4096,  256, 0, stream>>>(Wk, Wkb, 1048576);
    cvt_f32_bf16<<<4096,  256, 0, stream>>>(Wv, Wvb, 1048576);
    cvt_f32_bf16<<<16384, 256, 0, stream>>>(Wo, Wob, 4194304);

    // projections: X @ W^T
    gemm_bt<0><<<dim3(32, 32), 256, 0, stream>>>(hsb, Wqb, qb,  nullptr, 4096, 4096, 4096);
    gemm_bt<0><<<dim3(8, 32),  256, 0, stream>>>(hsb, Wkb, kbf, nullptr, 4096, 1024, 4096);
    gemm_bt<2><<<dim3(8, 32),  256, 0, stream>>>(hsb, Wvb, vbf, nullptr, 4096, 1024, 4096);

    // RoPE on Q (32 heads) and K (8 heads)
    rope_k<<<32768, 256, 0, stream>>>(qb,  11);
    rope_k<<<8192,  256, 0, stream>>>(kbf, 9);

    // causal flash attention -> ab [4096, 4096] bf16
    flash_attn<<<dim3(32, 32, 2), 256, 0, stream>>>(qb, kbf, vbf, ab);

    // output projection, fp32 epilogue straight to d_out
    gemm_bt<1><<<dim3(32, 32), 256, 0, stream>>>(ab, Wob, nullptr, out, 4096, 4096, 4096);
}

// Round 2
// 1144.780 us; speedup vs baseline: 1.3627x; 1.3627x over previous
//
#include <hip/hip_runtime.h>

typedef unsigned short u16;
typedef unsigned int u32;
typedef __attribute__((ext_vector_type(8))) short short8;
typedef __attribute__((ext_vector_type(4))) float f32x4;
typedef __attribute__((ext_vector_type(4))) u16 ushort4_t;

// ---------- scalar conversion helpers --------------------------------------
__device__ __forceinline__ float bf2f(u16 u) {
    u32 x = ((u32)u) << 16;
    return __uint_as_float(x);
}
__device__ __forceinline__ u16 f2bf(float f) {  // round-to-nearest-even
    u32 x = __float_as_uint(f);
    x += 0x7FFFu + ((x >> 16) & 1u);
    return (u16)(x >> 16);
}

// ---------- async global->LDS (16B per lane, wave-uniform base) ------------
using as1_cv = __attribute__((address_space(1))) const void;
using as3_v  = __attribute__((address_space(3))) void;
__device__ __forceinline__ void gld16(const void* g, void* l) {
    __builtin_amdgcn_global_load_lds((as1_cv*)g, (as3_v*)l, 16, 0, 0);
}

// ---------- fp32 -> bf16 convert (4 elems/thread) --------------------------
__global__ void cvt_f32_bf16(const float* __restrict__ in, u16* __restrict__ out, int n4) {
    int i = blockIdx.x * 256 + threadIdx.x;
    if (i >= n4) return;
    float4 v = ((const float4*)in)[i];
    ushort4_t o;
    o[0] = f2bf(v.x); o[1] = f2bf(v.y); o[2] = f2bf(v.z); o[3] = f2bf(v.w);
    ((ushort4_t*)out)[i] = o;
}

// ---------- GEMM: C[M,N] = A[M,K] * B[N,K]^T, bf16 inputs ------------------
// OUT_MODE: 0 = bf16 out, 1 = f32 out, 3 = bf16 TRANSPOSED out (Ct[N,M])
template <int OUT_MODE>
__global__ __launch_bounds__(256) void gemm_bt(
    const u16* __restrict__ A, const u16* __restrict__ B,
    u16* __restrict__ Cb, float* __restrict__ Cf,
    int M, int N, int K)
{
    __shared__ __align__(16) u16 As[128 * 32];
    __shared__ __align__(16) u16 Bs[128 * 32];
    const int t    = threadIdx.x;
    const int lane = t & 63;
    const int w    = t >> 6;
    const int wm   = w & 1;
    const int wn   = w >> 1;
    const int bx   = blockIdx.x;   // N tile
    const int by   = blockIdx.y;   // M tile

    const int r  = t >> 2;
    const int c8 = (t & 3) * 8;
    const u16* gA0 = A + (size_t)(by * 128 + r) * K + c8;
    const u16* gA1 = gA0 + (size_t)64 * K;
    const u16* gB0 = B + (size_t)(bx * 128 + r) * K + c8;
    const u16* gB1 = gB0 + (size_t)64 * K;
    u16* lA0 = &As[t * 8];
    u16* lA1 = &As[2048 + t * 8];
    u16* lB0 = &Bs[t * 8];
    u16* lB1 = &Bs[2048 + t * 8];

    f32x4 acc[4][4] = {};

    const int arow = wm * 64 + (lane & 15);
    const int brow = wn * 64 + (lane & 15);
    const int koff = (lane >> 4) * 8;

    for (int kt = 0; kt < K; kt += 32) {
        gld16(gA0 + kt, lA0);
        gld16(gA1 + kt, lA1);
        gld16(gB0 + kt, lB0);
        gld16(gB1 + kt, lB1);
        __syncthreads();
        short8 af[4], bf[4];
#pragma unroll
        for (int i = 0; i < 4; i++)
            af[i] = *(const short8*)&As[(arow + i * 16) * 32 + koff];
#pragma unroll
        for (int i = 0; i < 4; i++)
            bf[i] = *(const short8*)&Bs[(brow + i * 16) * 32 + koff];
#pragma unroll
        for (int mi = 0; mi < 4; mi++)
#pragma unroll
            for (int ni = 0; ni < 4; ni++)
                acc[mi][ni] = __builtin_amdgcn_mfma_f32_16x16x32_bf16(
                    af[mi], bf[ni], acc[mi][ni], 0, 0, 0);
        __syncthreads();
    }

    const int row0 = by * 128 + wm * 64 + (lane >> 4) * 4;
    const int col0 = bx * 128 + wn * 64 + (lane & 15);
#pragma unroll
    for (int mi = 0; mi < 4; mi++) {
#pragma unroll
        for (int ni = 0; ni < 4; ni++) {
            if (OUT_MODE == 3) {
                // transposed bf16: Ct[col][row], 4 consecutive rows -> 8B store
                ushort4_t o;
#pragma unroll
                for (int rr = 0; rr < 4; rr++) o[rr] = f2bf(acc[mi][ni][rr]);
                int col = col0 + ni * 16;
                *(ushort4_t*)&Cb[(size_t)col * M + row0 + mi * 16] = o;
            } else {
#pragma unroll
                for (int rr = 0; rr < 4; rr++) {
                    int row = row0 + mi * 16 + rr;
                    int col = col0 + ni * 16;
                    float v = acc[mi][ni][rr];
                    if (OUT_MODE == 1) Cf[(size_t)row * N + col] = v;
                    else               Cb[(size_t)row * N + col] = f2bf(v);
                }
            }
        }
    }
}

// ---------- RoPE in-place on bf16 [B*S, H*128] -----------------------------
__global__ void rope_k(u16* __restrict__ x, int hshift) {
    int idx = blockIdx.x * 256 + threadIdx.x;
    int i   = idx & 63;
    int hm  = (1 << (hshift - 6)) - 1;
    int h   = (idx >> 6) & hm;
    int row = idx >> hshift;       // 0..B*S-1
    int s   = row & 2047;          // position within sequence
    int stride = (hm + 1) * 128;
    size_t base = (size_t)row * stride + h * 128 + i;
    float th = (float)s * powf(10000.0f, -(float)i / 64.0f);
    float cs = cosf(th), sn = sinf(th);
    float x1 = bf2f(x[base]), x2 = bf2f(x[base + 64]);
    x[base]      = f2bf(x1 * cs - x2 * sn);
    x[base + 64] = f2bf(x2 * cs + x1 * sn);
}

// ---------- causal flash attention, LDS-staged K/V, all-bf16 x32 MFMA ------
// grid (16, NH, B); 256 thr = 4 waves; block = 128 q rows; wave w = 32 q rows
// (2 subtiles of 16 sharing K/V fragments). Per 32-key step:
//   scores: S^T = Kperm * Q^T  (A rows permuted: key(m) = (m>>2)*8+kk*4+(m&3))
//   -> C layout rows land exactly in PV B-operand key order g*8+j.
//   PV: O^T += V^T * P^T with V^T staged [dim][key] in LDS (ds_read_b128).
// K LDS is XOR-swizzled at 16B chunks so permuted-row reads cover 32 banks.
__global__ __launch_bounds__(256) void flash_attn(
    const u16* __restrict__ qb, const u16* __restrict__ kb,
    const u16* __restrict__ vt, u16* __restrict__ ob)
{
    __shared__ __align__(16) u16 Ks[32 * 128];
    __shared__ __align__(16) u16 Vs[128 * 32];
    const int t    = threadIdx.x;
    const int lane = t & 63;
    const int w    = t >> 6;
    const int col  = lane & 15;
    const int g    = lane >> 4;
    const int qt   = 15 - blockIdx.x;     // long tiles dispatch first
    const int qh   = blockIdx.y;
    const int b    = blockIdx.z;
    const int kvh  = qh >> 2;             // G = 4
    const int Q0   = qt * 128;
    const int qw   = Q0 + w * 32;

    // Q fragments (B-operand): Q[q][c*32 + g*8 + j]
    short8 qf[2][4];
#pragma unroll
    for (int sub = 0; sub < 2; sub++) {
        const u16* qrow = qb + ((size_t)(b * 2048 + qw + sub * 16 + col)) * 4096 + qh * 128;
#pragma unroll
        for (int c = 0; c < 4; c++)
            qf[sub][c] = *(const short8*)(qrow + c * 32 + g * 8);
    }

    const u16* kbase = kb + ((size_t)b * 2048) * 1024 + kvh * 128;
    const u16* vbase = vt + ((size_t)kvh * 128) * 4096 + (size_t)b * 2048;

    // K staging swizzle constants (per-thread, loop-invariant)
    const int key_s0 = t >> 4;            // staged key (issue 0), issue1 = +16
    const int sw0 = (key_s0 & 3) ^ ((key_s0 & 8) >> 1);
    const int sw1 = ((key_s0 + 16) & 3) ^ (((key_s0 + 16) & 8) >> 1);  // == sw0
    const int cc0 = (t & 15) ^ sw0;
    const int cc1 = (t & 15) ^ sw1;
    const int vd0 = t >> 2;               // staged V dim (issue 0), issue1 = +64
    const int vko = (t & 3) * 8;

    // K read chunk ids: chunk(key,cc) at key*16 + (cc ^ sw(key)), cc = c*4+g
    int kcid[2][4];
#pragma unroll
    for (int kk = 0; kk < 2; kk++) {
        int key = ((col >> 2) * 8) + kk * 4 + (col & 3);
        int sw = (key & 3) ^ ((key & 8) >> 1);
#pragma unroll
        for (int c = 0; c < 4; c++)
            kcid[kk][c] = key * 16 + ((c * 4 + g) ^ sw);
    }
    const int vcidb = col * 4 + g;        // V chunk = (dt*16+col)*4 + g

    float m_run[2] = {-1e30f, -1e30f};
    float l_run[2] = {0.f, 0.f};
    f32x4 ot[2][8] = {};
    const float scale = 0.08838834764831845f;  // 1/sqrt(128)

    const int nsteps = (Q0 + 128) >> 5;
    const int qmax_w = qw + 31;

    for (int step = 0; step < nsteps; step++) {
        const int k0 = step * 32;
        // stage K tile [32 keys][128 dims] (swizzled) + V^T tile [128][32]
        gld16(kbase + (size_t)(k0 + key_s0) * 1024 + cc0 * 8, (u16*)Ks + t * 8);
        gld16(kbase + (size_t)(k0 + key_s0 + 16) * 1024 + cc1 * 8, (u16*)Ks + 2048 + t * 8);
        gld16(vbase + (size_t)vd0 * 4096 + k0 + vko, (u16*)Vs + t * 8);
        gld16(vbase + (size_t)(vd0 + 64) * 4096 + k0 + vko, (u16*)Vs + 2048 + t * 8);
        __syncthreads();

        if (k0 <= qmax_w) {
            // scores
            f32x4 sc[2][2] = {};
#pragma unroll
            for (int c = 0; c < 4; c++) {
#pragma unroll
                for (int kk = 0; kk < 2; kk++) {
                    short8 kf = *(const short8*)(Ks + kcid[kk][c] * 8);
                    sc[0][kk] = __builtin_amdgcn_mfma_f32_16x16x32_bf16(kf, qf[0][c], sc[0][kk], 0, 0, 0);
                    sc[1][kk] = __builtin_amdgcn_mfma_f32_16x16x32_bf16(kf, qf[1][c], sc[1][kk], 0, 0, 0);
                }
            }
            // online softmax per subtile; lane holds keys k0 + g*8 + kk*4 + rr
            short8 pf[2];
#pragma unroll
            for (int sub = 0; sub < 2; sub++) {
                const int q = qw + sub * 16 + col;
                float s[8];
                float tmax = -1e30f;
#pragma unroll
                for (int kk = 0; kk < 2; kk++)
#pragma unroll
                    for (int rr = 0; rr < 4; rr++) {
                        int key = k0 + g * 8 + kk * 4 + rr;
                        float v = sc[sub][kk][rr] * scale;
                        v = (key <= q) ? v : -1e30f;
                        s[kk * 4 + rr] = v;
                        tmax = fmaxf(tmax, v);
                    }
                tmax = fmaxf(tmax, __shfl_xor(tmax, 16));
                tmax = fmaxf(tmax, __shfl_xor(tmax, 32));
                float m_new = fmaxf(m_run[sub], tmax);
                float alpha = __expf(m_run[sub] - m_new);
                float tsum = 0.f;
#pragma unroll
                for (int j = 0; j < 8; j++) {
                    float e = (s[j] > -0.9e30f) ? __expf(s[j] - m_new) : 0.f;
                    ((u16*)&pf[sub])[j] = f2bf(e);
                    tsum += e;
                }
                tsum += __shfl_xor(tsum, 16);
                tsum += __shfl_xor(tsum, 32);
                l_run[sub] = l_run[sub] * alpha + tsum;
                m_run[sub] = m_new;
#pragma unroll
                for (int dt = 0; dt < 8; dt++)
#pragma unroll
                    for (int rr = 0; rr < 4; rr++) ot[sub][dt][rr] *= alpha;
            }
            // PV: O^T += V^T * P^T
#pragma unroll
            for (int dt = 0; dt < 8; dt++) {
                short8 vf = *(const short8*)(Vs + (vcidb + dt * 64) * 8);
                ot[0][dt] = __builtin_amdgcn_mfma_f32_16x16x32_bf16(vf, pf[0], ot[0][dt], 0, 0, 0);
                ot[1][dt] = __builtin_amdgcn_mfma_f32_16x16x32_bf16(vf, pf[1], ot[1][dt], 0, 0, 0);
            }
        }
        __syncthreads();
    }

    // epilogue: O^T C-layout: dim = dt*16 + g*4 + rr, query = col
#pragma unroll
    for (int sub = 0; sub < 2; sub++) {
        float inv = 1.0f / l_run[sub];
        u16* orow = ob + ((size_t)(b * 2048 + qw + sub * 16 + col)) * 4096 + qh * 128;
#pragma unroll
        for (int dt = 0; dt < 8; dt++) {
            ushort4_t o;
#pragma unroll
            for (int rr = 0; rr < 4; rr++) o[rr] = f2bf(ot[sub][dt][rr] * inv);
            *(ushort4_t*)(orow + dt * 16 + g * 4) = o;
        }
    }
}

// ---------------------------------------------------------------------------
extern "C" void kernel_launch(void* const* d_in, const int* in_sizes, int n_in,
                              void* d_out, int out_size, void* d_ws, size_t ws_size,
                              hipStream_t stream) {
    const float* hs = (const float*)d_in[0];  // [2,2048,4096]
    const float* Wq = (const float*)d_in[1];  // [4096,4096]
    const float* Wk = (const float*)d_in[2];  // [1024,4096]
    const float* Wv = (const float*)d_in[3];  // [1024,4096]
    const float* Wo = (const float*)d_in[4];  // [4096,4096]
    float* out = (float*)d_out;               // [2,2048,4096]

    char* ws = (char*)d_ws;
    u16* hsb = (u16*)(ws + 0);           // [4096,4096] bf16
    u16* Wqb = (u16*)(ws + 33554432);
    u16* Wkb = (u16*)(ws + 67108864);
    u16* Wvb = (u16*)(ws + 75497472);
    u16* Wob = (u16*)(ws + 83886080);
    u16* qb  = (u16*)(ws + 117440512);   // [4096,4096] bf16
    u16* kbf = (u16*)(ws + 150994944);   // [4096,1024] bf16
    u16* vtb = (u16*)(ws + 159383552);   // [1024,4096] bf16 (V transposed)
    u16* ab  = hsb;                      // alias: hs dead after QKV GEMMs

    cvt_f32_bf16<<<16384, 256, 0, stream>>>(hs, hsb, 4194304);
    cvt_f32_bf16<<<16384, 256, 0, stream>>>(Wq, Wqb, 4194304);
    cvt_f32_bf16<<<4096,  256, 0, stream>>>(Wk, Wkb, 1048576);
    cvt_f32_bf16<<<4096,  256, 0, stream>>>(Wv, Wvb, 1048576);
    cvt_f32_bf16<<<16384, 256, 0, stream>>>(Wo, Wob, 4194304);

    gemm_bt<0><<<dim3(32, 32), 256, 0, stream>>>(hsb, Wqb, qb,  nullptr, 4096, 4096, 4096);
    gemm_bt<0><<<dim3(8, 32),  256, 0, stream>>>(hsb, Wkb, kbf, nullptr, 4096, 1024, 4096);
    gemm_bt<3><<<dim3(8, 32),  256, 0, stream>>>(hsb, Wvb, vtb, nullptr, 4096, 1024, 4096);

    rope_k<<<32768, 256, 0, stream>>>(qb,  11);
    rope_k<<<8192,  256, 0, stream>>>(kbf, 9);

    flash_attn<<<dim3(16, 32, 2), 256, 0, stream>>>(qb, kbf, vtb, ab);

    gemm_bt<1><<<dim3(32, 32), 256, 0, stream>>>(ab, Wob, nullptr, out, 4096, 4096, 4096);
}